// Round 11
// baseline (233.052 us; speedup 1.0000x reference)
//
#include <hip/hip_runtime.h>
#include <stdint.h>

typedef uint16_t u16;
typedef __attribute__((ext_vector_type(8)))  __bf16    bf16x8;
typedef __attribute__((ext_vector_type(4)))  __bf16    bf16x4;
typedef __attribute__((ext_vector_type(8)))  uint16_t  u16x8;
typedef __attribute__((ext_vector_type(4)))  uint16_t  u16x4;
typedef __attribute__((ext_vector_type(4)))  float     f32x4;

#define LOG2E 1.44269504088896340736f
#define MFMA16(a, b, c) __builtin_amdgcn_mfma_f32_16x16x32_bf16((a), (b), (c), 0, 0, 0)

__device__ __forceinline__ u16 f2b(float f) {   // fp32 -> bf16 RNE
  uint32_t u = __builtin_bit_cast(uint32_t, f);
  u += 0x7fffu + ((u >> 16) & 1u);
  return (u16)(u >> 16);
}

// LDS tiles: [rows][64 bf16] = 8 chunks of 16B per row, chunk XOR-swizzled by row&7.
__device__ __forceinline__ bf16x8 ldsFrag(const u16* base, int row, int chunk) {
  const u16* p = base + row * 64 + ((chunk ^ (row & 7)) << 3);
  u16x8 raw = *(const u16x8*)p;
  return __builtin_bit_cast(bf16x8, raw);
}
__device__ __forceinline__ void ldsPut(u16* base, int row, int logicalChunk, u16x8 v) {
  u16* p = base + row * 64 + ((logicalChunk ^ (row & 7)) << 3);
  *(u16x8*)p = v;
}

// async global->LDS DMA, 16B per lane; LDS dest = wave-uniform base + lane*16.
__device__ __forceinline__ void dma16(const u16* g, u16* l) {
  __builtin_amdgcn_global_load_lds(
      (const __attribute__((address_space(1))) uint32_t*)g,
      (__attribute__((address_space(3))) uint32_t*)l, 16, 0, 0);
}

// ---------------- kernel X: x fp32 -> bf16 (one shot) -----------------------
__global__ __launch_bounds__(256) void xconv(
    const float* __restrict__ x, u16* __restrict__ xb) {
  size_t idx = ((size_t)blockIdx.x * 256 + threadIdx.x) * 8;  // 4096 blocks x 8 elems
  f32x4 a0 = *(const f32x4*)(x + idx);
  f32x4 a1 = *(const f32x4*)(x + idx + 4);
  u16x8 v;
#pragma unroll
  for (int i = 0; i < 4; ++i) { v[i] = f2b(a0[i]); v[4 + i] = f2b(a1[i]); }
  *(u16x8*)(xb + idx) = v;
}

// ---------------- kernel 0: pack weights (coalesced read + LDS transpose) ----
// Wt[n][k] bf16 (n<64: Wf*log2e, n<128: Wg, else Wh), biasc[n] fp32 (bf*log2e).
__global__ __launch_bounds__(256) void pack_weights2(
    const float* __restrict__ Wf, const float* __restrict__ Wg,
    const float* __restrict__ Wh, const float* __restrict__ bfv,
    const float* __restrict__ bgv, const float* __restrict__ bhv,
    u16* __restrict__ Wt, float* __restrict__ biasc) {
  __shared__ u16 T[64 * 64];       // [k][n]
  const int nt = blockIdx.x >> 3;  // 0..9
  const int kt = blockIdx.x & 7;   // 0..7
  const int n0 = nt * 64, k0 = kt * 64;
  const float* src; int stride, cbase; float scale = 1.0f;
  if (nt == 0)      { src = Wf; stride = 64;  cbase = 0;        scale = LOG2E; }
  else if (nt == 1) { src = Wg; stride = 64;  cbase = 0; }
  else              { src = Wh; stride = 512; cbase = n0 - 128; }
  const int t = threadIdx.x;
  const int cl = (t & 15) * 4, r0 = t >> 4;
#pragma unroll
  for (int j = 0; j < 4; ++j) {
    int r = r0 + j * 16;
    f32x4 v = *(const f32x4*)(src + (size_t)(k0 + r) * stride + cbase + cl);
    u16x4 o;
#pragma unroll
    for (int i = 0; i < 4; ++i) o[i] = f2b(v[i] * scale);
    *(u16x4*)(T + r * 64 + cl) = o;
  }
  __syncthreads();
  const int n = t >> 2, kq = (t & 3) * 16;
  u16x8 a, b2;
#pragma unroll
  for (int i = 0; i < 8; ++i) { a[i] = T[(kq + i) * 64 + n]; b2[i] = T[(kq + 8 + i) * 64 + n]; }
  *(u16x8*)(Wt + (size_t)(n0 + n) * 512 + k0 + kq) = a;
  *(u16x8*)(Wt + (size_t)(n0 + n) * 512 + k0 + kq + 8) = b2;
  if (kt == 0 && t < 64) {
    float bv = (nt == 0) ? bfv[t] * LOG2E : (nt == 1) ? bgv[t] : bhv[cbase + t];
    biasc[n0 + t] = bv;
  }
}

// ---------------- kernel 1: projection GEMM (all-bf16, all-DMA staging) -----
// [16384 x 512](xb bf16) @ Wt^T -> f[m][64], g[m][64], ht[b][vcol][pos]
__global__ __launch_bounds__(256, 2) void proj_gemm(
    const u16* __restrict__ xb, const u16* __restrict__ Wt,
    const float* __restrict__ biasc,
    u16* __restrict__ fo, u16* __restrict__ go, u16* __restrict__ ht) {
  __shared__ u16 smem[128 * 128];          // 32KB: lds_a | lds_b, reused as T
  u16* lds_a = smem;
  u16* lds_b = smem + 128 * 64;
  const int t = threadIdx.x, lane = t & 63, wave = t >> 6;
  const int m0 = blockIdx.x * 128, n0 = blockIdx.y * 128;
  const int wr = wave >> 1, wc = wave & 1;
  const int l15 = lane & 15, l4 = lane >> 4;
  const int dmarow = lane >> 3, dmachunk = (lane & 7) ^ (lane >> 3);

  f32x4 acc[4][4];
#pragma unroll
  for (int i = 0; i < 4; ++i)
#pragma unroll
    for (int j = 0; j < 4; ++j) acc[i][j] = (f32x4)(0.f);

  for (int kb = 0; kb < 8; ++kb) {
    const int k0 = kb * 64;
    if (kb) __syncthreads();               // prior MFMA LDS reads done
#pragma unroll
    for (int ii = 0; ii < 4; ++ii) {       // stage A: xb rows (m)
      int rw = wave * 32 + ii * 8;
      dma16(xb + (size_t)(m0 + rw + dmarow) * 512 + k0 + dmachunk * 8,
            lds_a + rw * 64);
    }
#pragma unroll
    for (int ii = 0; ii < 4; ++ii) {       // stage B: Wt rows (n)
      int rw = wave * 32 + ii * 8;
      dma16(Wt + (size_t)(n0 + rw + dmarow) * 512 + k0 + dmachunk * 8,
            lds_b + rw * 64);
    }
    __syncthreads();                       // drains DMA (vmcnt(0) at barrier)
#pragma unroll
    for (int ks = 0; ks < 2; ++ks) {
      const int chunk = ks * 4 + l4;
      bf16x8 af[4], bq[4];
#pragma unroll
      for (int mt = 0; mt < 4; ++mt) af[mt] = ldsFrag(lds_a, wr * 64 + mt * 16 + l15, chunk);
#pragma unroll
      for (int nt = 0; nt < 4; ++nt) bq[nt] = ldsFrag(lds_b, wc * 64 + nt * 16 + l15, chunk);
#pragma unroll
      for (int mt = 0; mt < 4; ++mt)
#pragma unroll
        for (int nt = 0; nt < 4; ++nt) acc[mt][nt] = MFMA16(af[mt], bq[nt], acc[mt][nt]);
    }
  }

  if (n0 >= 128) {
    // ---- h path: LDS-bounce transpose, coalesced ht stores ----
    __syncthreads();                       // all MFMA LDS reads done
#pragma unroll
    for (int nt = 0; nt < 4; ++nt) {
      int nl = wc * 64 + nt * 16 + l15;    // n within block (0..127)
      float bv = biasc[n0 + nl];
#pragma unroll
      for (int mt = 0; mt < 4; ++mt) {
        int mb = wr * 64 + mt * 16 + (l4 << 2);
        f32x4 a = acc[mt][nt];
        u16x4 v;
#pragma unroll
        for (int r = 0; r < 4; ++r) v[r] = f2b(a[r] + bv);
        // T[nl][m], 16B-chunk swizzled by nl&7
        u16* dst = smem + nl * 128 + (((mb >> 3) ^ (nl & 7)) << 3) + (mb & 7);
        *(u16x4*)dst = v;
      }
    }
    __syncthreads();
    const int bb = m0 >> 12, posb = m0 & 4095;
    const int row0 = t >> 4, c16 = t & 15;
#pragma unroll
    for (int j = 0; j < 8; ++j) {
      int rr = row0 + j * 16;
      u16x8 v = *(const u16x8*)(smem + rr * 128 + ((c16 ^ (rr & 7)) << 3));
      int vcol = n0 - 128 + rr;
      *(u16x8*)(ht + ((size_t)(bb * 512 + vcol) << 12) + posb + c16 * 8) = v;
    }
  } else {
    // ---- f/g path ----
#pragma unroll
    for (int nt = 0; nt < 4; ++nt) {
      int n = wc * 64 + nt * 16 + l15;
      float bv = biasc[n];
#pragma unroll
      for (int mt = 0; mt < 4; ++mt) {
        int mrow = m0 + wr * 64 + mt * 16 + (l4 << 2);
        f32x4 a = acc[mt][nt];
        if (n < 64) {
#pragma unroll
          for (int r = 0; r < 4; ++r) fo[(size_t)(mrow + r) * 64 + n] = f2b(a[r] + bv);
        } else {
#pragma unroll
          for (int r = 0; r < 4; ++r) go[(size_t)(mrow + r) * 64 + (n - 64)] = f2b(a[r] + bv);
        }
      }
    }
  }
}

// ---------------- kernel 2: flash attention v13 (128q x 256c, vq halved) ----
// attn12 confirmed the L2-traffic model (163->128us); counters now show
// VALUBusy 30% with softmax duplicated 4x across vq slices. This kernel
// halves the vq redundancy: block = 128 q x 256 c, 16 waves (1024 thr),
// 256 blocks -> 1 block/CU, same 16 waves/CU. QK MFMA 68.7->34.3 GF,
// softmax VALU halved; traffic ~unchanged (below the L2 wall). S^T role
// (kq=w&3, qh=w>>2): 16 keys x 32 q (4 MFMA + 2-qt softmax). PV role:
// wave owns 16 c x all 128 q (16 MFMA, 2 hb loads). Kt=64, 2 barriers/iter,
// all swizzles/layout atoms verbatim from attn12.
__global__ __launch_bounds__(1024, 4) void attn13(
    const u16* __restrict__ fq, const u16* __restrict__ gk,
    const u16* __restrict__ ht, const float* __restrict__ x,
    const float* __restrict__ gamma_p, float* __restrict__ out) {
  __shared__ u16 lds_g[64 * 64];     // [key][d] swizzled, 8KB
  __shared__ u16 lds_p[128 * 64];    // [q][key] swizzled, 16KB
  __shared__ float lds_red[16 * 32];
  __shared__ float lds_linv[128];

  const int i = blockIdx.x;          // 256 blocks
  const int slice = i & 7;           // XCD x serves slice x: ht 2MB + g in its L2
  const int b = slice >> 1, vq = slice & 1;
  const int qb = i >> 3;             // 0..31
  const int q0 = qb * 128, vc0 = vq * 256;

  const int t = threadIdx.x, lane = t & 63, w = t >> 6;   // w: 0..15
  const int l15 = lane & 15, l4 = lane >> 4;
  const int kq = w & 3, qh = w >> 2; // S^T role: key-quarter, q-quarter (32 q)
  const float gamma = gamma_p[0];
  const int dmarow = lane >> 3, dmachunk = (lane & 7) ^ (lane >> 3);

  const u16* gkb = gk + (size_t)(b * 4096) * 64;
  const u16* htw = ht + ((size_t)(b * 512 + vc0 + w * 16)) * 4096;

  // preload f frags (B-operand for S^T): this wave's 32 q
  bf16x8 fB[2][2];
#pragma unroll
  for (int qt = 0; qt < 2; ++qt)
#pragma unroll
    for (int ks = 0; ks < 2; ++ks) {
      const u16* p = fq + (size_t)(b * 4096 + q0 + qh * 32 + qt * 16 + l15) * 64 + ks * 32 + l4 * 8;
      fB[qt][ks] = __builtin_bit_cast(bf16x8, *(const u16x8*)p);
    }

  f32x4 oacc[8];                     // 16 c x 128 q (8 q-tiles)
#pragma unroll
  for (int qt = 0; qt < 8; ++qt) oacc[qt] = (f32x4)(0.f);
  float lrun[2] = {0.f, 0.f};

  auto stage_g = [&](int k0g) {      // stage 64 keys x 64 d; waves 0..7 do 8 rows
    if (w < 8) {
      const u16* src = gkb + (size_t)(k0g + w * 8 + dmarow) * 64 + dmachunk * 8;
      dma16(src, lds_g + (w * 8) * 64);
    }
  };

  stage_g(0);
  __syncthreads();

  for (int kt = 0; kt < 64; ++kt) {
    const int k0 = kt * 64;
    // ---- S^T: keys kq*16..+16, q = qh*32..+32 ----
    f32x4 sacc[2];
#pragma unroll
    for (int qt = 0; qt < 2; ++qt) sacc[qt] = (f32x4)(0.f);
#pragma unroll
    for (int ks = 0; ks < 2; ++ks) {
      bf16x8 gA = ldsFrag(lds_g, kq * 16 + l15, ks * 4 + l4);
#pragma unroll
      for (int qt = 0; qt < 2; ++qt) sacc[qt] = MFMA16(gA, fB[qt][ks], sacc[qt]);
    }
    // exp2 (log2e pre-folded), packed b64 P-write, per-lane row-sum partials
#pragma unroll
    for (int qt = 0; qt < 2; ++qt) {
      f32x4 s = sacc[qt];
      f32x4 p;
#pragma unroll
      for (int r = 0; r < 4; ++r) p[r] = __builtin_amdgcn_exp2f(s[r]);
      lrun[qt] += (p[0] + p[1]) + (p[2] + p[3]);
      bf16x4 pb;
#pragma unroll
      for (int r = 0; r < 4; ++r) pb[r] = (__bf16)p[r];
      int row = qh * 32 + qt * 16 + l15;       // q within block (0..127)
      int keyb = kq * 16 + (l4 << 2);          // 4 consecutive keys
      u16* dst = lds_p + row * 64 + (((keyb >> 3) ^ (row & 7)) << 3) + (keyb & 7);
      *(u16x4*)dst = __builtin_bit_cast(u16x4, pb);
    }
    __syncthreads();                 // P visible; lds_g reads done
    if (kt < 63) stage_g(k0 + 64);   // overlap g DMA with PV
    // ---- PV: O[q][c] += P . ht, wave owns 16 c x 128 q ----
#pragma unroll
    for (int ks = 0; ks < 2; ++ks) {
      const u16* hp = htw + (size_t)l15 * 4096 + k0 + ks * 32 + l4 * 8;
      bf16x8 hb = __builtin_bit_cast(bf16x8, *(const u16x8*)hp);
#pragma unroll
      for (int qt = 0; qt < 8; ++qt) {
        bf16x8 pf = ldsFrag(lds_p, qt * 16 + l15, ks * 4 + l4);
        oacc[qt] = MFMA16(pf, hb, oacc[qt]);
      }
    }
    __syncthreads();                 // PV lds_p reads done; g(kt+1) drained
  }

  // ---- row-sum reduction: wave partials -> cross-wave (4 kq) combine ----
#pragma unroll
  for (int qt = 0; qt < 2; ++qt) {
    lrun[qt] += __shfl_xor(lrun[qt], 16);
    lrun[qt] += __shfl_xor(lrun[qt], 32);
  }
  if (l4 == 0) {
#pragma unroll
    for (int qt = 0; qt < 2; ++qt) lds_red[w * 32 + qt * 16 + l15] = lrun[qt];
  }
  __syncthreads();
  if (t < 128) {                     // q = t; waves qh*4+kq (kq=0..3) hold keys
    int qhh = t >> 5, loc = t & 31;
    float s = (lds_red[(qhh * 4 + 0) * 32 + loc] + lds_red[(qhh * 4 + 1) * 32 + loc]) +
              (lds_red[(qhh * 4 + 2) * 32 + loc] + lds_red[(qhh * 4 + 3) * 32 + loc]);
    lds_linv[t] = 1.0f / s;
  }
  __syncthreads();

  // ---- epilogue: out = x + gamma * O / l ----
#pragma unroll
  for (int qt = 0; qt < 8; ++qt) {
    f32x4 linv = *(const f32x4*)&lds_linv[qt * 16 + (l4 << 2)];
    int c = vc0 + w * 16 + l15;
#pragma unroll
    for (int r = 0; r < 4; ++r) {
      int q = q0 + qt * 16 + (l4 << 2) + r;
      size_t idx = ((size_t)(b * 4096 + q) << 9) + c;
      out[idx] = x[idx] + gamma * oacc[qt][r] * linv[r];
    }
  }
}

extern "C" void kernel_launch(void* const* d_in, const int* in_sizes, int n_in,
                              void* d_out, int out_size, void* d_ws, size_t ws_size,
                              hipStream_t stream) {
  const float* x   = (const float*)d_in[0];
  const float* Wf  = (const float*)d_in[1];
  const float* bfv = (const float*)d_in[2];
  const float* Wg  = (const float*)d_in[3];
  const float* bgv = (const float*)d_in[4];
  const float* Wh  = (const float*)d_in[5];
  const float* bhv = (const float*)d_in[6];
  const float* gam = (const float*)d_in[7];
  float* out = (float*)d_out;

  char* ws = (char*)d_ws;                  // total scratch: ~38.4 MB
  u16*   Wt    = (u16*)(ws);               // 640*512*2    = 655360
  float* biasc = (float*)(ws + 655360);    // 640*4        = 2560
  u16*   fo    = (u16*)(ws + 657920);      // 16384*64*2   = 2097152
  u16*   go    = (u16*)(ws + 2755072);     // 2097152
  u16*   ht    = (u16*)(ws + 4852224);     // 4*512*4096*2 = 16777216
  u16*   xb    = (u16*)(ws + 21629440);    // 16384*512*2  = 16777216

  xconv<<<4096, 256, 0, stream>>>(x, xb);
  pack_weights2<<<80, 256, 0, stream>>>(Wf, Wg, Wh, bfv, bgv, bhv, Wt, biasc);
  proj_gemm<<<dim3(128, 5), 256, 0, stream>>>(xb, Wt, biasc, fo, go, ht);
  attn13<<<256, 1024, 0, stream>>>(fo, go, ht, x, gam, out);
}

// Round 12
// 223.465 us; speedup vs baseline: 1.0429x; 1.0429x over previous
//
#include <hip/hip_runtime.h>
#include <stdint.h>

typedef uint16_t u16;
typedef __attribute__((ext_vector_type(8)))  __bf16    bf16x8;
typedef __attribute__((ext_vector_type(4)))  __bf16    bf16x4;
typedef __attribute__((ext_vector_type(8)))  uint16_t  u16x8;
typedef __attribute__((ext_vector_type(4)))  uint16_t  u16x4;
typedef __attribute__((ext_vector_type(4)))  float     f32x4;

#define LOG2E 1.44269504088896340736f
#define MFMA16(a, b, c) __builtin_amdgcn_mfma_f32_16x16x32_bf16((a), (b), (c), 0, 0, 0)

__device__ __forceinline__ u16 f2b(float f) {   // fp32 -> bf16 RNE
  uint32_t u = __builtin_bit_cast(uint32_t, f);
  u += 0x7fffu + ((u >> 16) & 1u);
  return (u16)(u >> 16);
}

// LDS tiles: [rows][64 bf16] = 8 chunks of 16B per row, chunk XOR-swizzled by row&7.
__device__ __forceinline__ bf16x8 ldsFrag(const u16* base, int row, int chunk) {
  const u16* p = base + row * 64 + ((chunk ^ (row & 7)) << 3);
  u16x8 raw = *(const u16x8*)p;
  return __builtin_bit_cast(bf16x8, raw);
}
__device__ __forceinline__ void ldsPut(u16* base, int row, int logicalChunk, u16x8 v) {
  u16* p = base + row * 64 + ((logicalChunk ^ (row & 7)) << 3);
  *(u16x8*)p = v;
}

// async global->LDS DMA, 16B per lane; LDS dest = wave-uniform base + lane*16.
__device__ __forceinline__ void dma16(const u16* g, u16* l) {
  __builtin_amdgcn_global_load_lds(
      (const __attribute__((address_space(1))) uint32_t*)g,
      (__attribute__((address_space(3))) uint32_t*)l, 16, 0, 0);
}

// ---------------- kernel 0: fused xconv + pack_weights ----------------------
// blocks 0..4095: x fp32 -> bf16 (xb). blocks 4096..4175: weight pack
// (Wt[n][k] bf16; n<64: Wf*log2e, n<128: Wg, else Wh; biasc fp32).
// One launch instead of two (saves a launch gap; outputs disjoint).
__global__ __launch_bounds__(256) void xpack(
    const float* __restrict__ x, u16* __restrict__ xb,
    const float* __restrict__ Wf, const float* __restrict__ Wg,
    const float* __restrict__ Wh, const float* __restrict__ bfv,
    const float* __restrict__ bgv, const float* __restrict__ bhv,
    u16* __restrict__ Wt, float* __restrict__ biasc) {
  __shared__ u16 T[64 * 64];       // [k][n] (pack branch only)
  const int t = threadIdx.x;
  if (blockIdx.x < 4096) {
    // ---- xconv branch ----
    size_t idx = ((size_t)blockIdx.x * 256 + t) * 8;
    f32x4 a0 = *(const f32x4*)(x + idx);
    f32x4 a1 = *(const f32x4*)(x + idx + 4);
    u16x8 v;
#pragma unroll
    for (int i = 0; i < 4; ++i) { v[i] = f2b(a0[i]); v[4 + i] = f2b(a1[i]); }
    *(u16x8*)(xb + idx) = v;
    return;
  }
  // ---- pack branch ----
  const int bid = blockIdx.x - 4096;
  const int nt = bid >> 3;         // 0..9
  const int kt = bid & 7;          // 0..7
  const int n0 = nt * 64, k0 = kt * 64;
  const float* src; int stride, cbase; float scale = 1.0f;
  if (nt == 0)      { src = Wf; stride = 64;  cbase = 0;        scale = LOG2E; }
  else if (nt == 1) { src = Wg; stride = 64;  cbase = 0; }
  else              { src = Wh; stride = 512; cbase = n0 - 128; }
  const int cl = (t & 15) * 4, r0 = t >> 4;
#pragma unroll
  for (int j = 0; j < 4; ++j) {
    int r = r0 + j * 16;
    f32x4 v = *(const f32x4*)(src + (size_t)(k0 + r) * stride + cbase + cl);
    u16x4 o;
#pragma unroll
    for (int i = 0; i < 4; ++i) o[i] = f2b(v[i] * scale);
    *(u16x4*)(T + r * 64 + cl) = o;
  }
  __syncthreads();
  const int n = t >> 2, kq = (t & 3) * 16;
  u16x8 a, b2;
#pragma unroll
  for (int i = 0; i < 8; ++i) { a[i] = T[(kq + i) * 64 + n]; b2[i] = T[(kq + 8 + i) * 64 + n]; }
  *(u16x8*)(Wt + (size_t)(n0 + n) * 512 + k0 + kq) = a;
  *(u16x8*)(Wt + (size_t)(n0 + n) * 512 + k0 + kq + 8) = b2;
  if (kt == 0 && t < 64) {
    float bv = (nt == 0) ? bfv[t] * LOG2E : (nt == 1) ? bgv[t] : bhv[cbase + t];
    biasc[n0 + t] = bv;
  }
}

// ---------------- kernel 1: projection GEMM (all-bf16, all-DMA staging) -----
// [16384 x 512](xb bf16) @ Wt^T -> f[m][64], g[m][64], ht[b][vcol][pos]
__global__ __launch_bounds__(256, 2) void proj_gemm(
    const u16* __restrict__ xb, const u16* __restrict__ Wt,
    const float* __restrict__ biasc,
    u16* __restrict__ fo, u16* __restrict__ go, u16* __restrict__ ht) {
  __shared__ u16 smem[128 * 128];          // 32KB: lds_a | lds_b, reused as T
  u16* lds_a = smem;
  u16* lds_b = smem + 128 * 64;
  const int t = threadIdx.x, lane = t & 63, wave = t >> 6;
  const int m0 = blockIdx.x * 128, n0 = blockIdx.y * 128;
  const int wr = wave >> 1, wc = wave & 1;
  const int l15 = lane & 15, l4 = lane >> 4;
  const int dmarow = lane >> 3, dmachunk = (lane & 7) ^ (lane >> 3);

  f32x4 acc[4][4];
#pragma unroll
  for (int i = 0; i < 4; ++i)
#pragma unroll
    for (int j = 0; j < 4; ++j) acc[i][j] = (f32x4)(0.f);

  for (int kb = 0; kb < 8; ++kb) {
    const int k0 = kb * 64;
    if (kb) __syncthreads();               // prior MFMA LDS reads done
#pragma unroll
    for (int ii = 0; ii < 4; ++ii) {       // stage A: xb rows (m)
      int rw = wave * 32 + ii * 8;
      dma16(xb + (size_t)(m0 + rw + dmarow) * 512 + k0 + dmachunk * 8,
            lds_a + rw * 64);
    }
#pragma unroll
    for (int ii = 0; ii < 4; ++ii) {       // stage B: Wt rows (n)
      int rw = wave * 32 + ii * 8;
      dma16(Wt + (size_t)(n0 + rw + dmarow) * 512 + k0 + dmachunk * 8,
            lds_b + rw * 64);
    }
    __syncthreads();                       // drains DMA (vmcnt(0) at barrier)
#pragma unroll
    for (int ks = 0; ks < 2; ++ks) {
      const int chunk = ks * 4 + l4;
      bf16x8 af[4], bq[4];
#pragma unroll
      for (int mt = 0; mt < 4; ++mt) af[mt] = ldsFrag(lds_a, wr * 64 + mt * 16 + l15, chunk);
#pragma unroll
      for (int nt = 0; nt < 4; ++nt) bq[nt] = ldsFrag(lds_b, wc * 64 + nt * 16 + l15, chunk);
#pragma unroll
      for (int mt = 0; mt < 4; ++mt)
#pragma unroll
        for (int nt = 0; nt < 4; ++nt) acc[mt][nt] = MFMA16(af[mt], bq[nt], acc[mt][nt]);
    }
  }

  if (n0 >= 128) {
    // ---- h path: LDS-bounce transpose, coalesced ht stores ----
    __syncthreads();                       // all MFMA LDS reads done
#pragma unroll
    for (int nt = 0; nt < 4; ++nt) {
      int nl = wc * 64 + nt * 16 + l15;    // n within block (0..127)
      float bv = biasc[n0 + nl];
#pragma unroll
      for (int mt = 0; mt < 4; ++mt) {
        int mb = wr * 64 + mt * 16 + (l4 << 2);
        f32x4 a = acc[mt][nt];
        u16x4 v;
#pragma unroll
        for (int r = 0; r < 4; ++r) v[r] = f2b(a[r] + bv);
        // T[nl][m], 16B-chunk swizzled by nl&7
        u16* dst = smem + nl * 128 + (((mb >> 3) ^ (nl & 7)) << 3) + (mb & 7);
        *(u16x4*)dst = v;
      }
    }
    __syncthreads();
    const int bb = m0 >> 12, posb = m0 & 4095;
    const int row0 = t >> 4, c16 = t & 15;
#pragma unroll
    for (int j = 0; j < 8; ++j) {
      int rr = row0 + j * 16;
      u16x8 v = *(const u16x8*)(smem + rr * 128 + ((c16 ^ (rr & 7)) << 3));
      int vcol = n0 - 128 + rr;
      *(u16x8*)(ht + ((size_t)(bb * 512 + vcol) << 12) + posb + c16 * 8) = v;
    }
  } else {
    // ---- f/g path ----
#pragma unroll
    for (int nt = 0; nt < 4; ++nt) {
      int n = wc * 64 + nt * 16 + l15;
      float bv = biasc[n];
#pragma unroll
      for (int mt = 0; mt < 4; ++mt) {
        int mrow = m0 + wr * 64 + mt * 16 + (l4 << 2);
        f32x4 a = acc[mt][nt];
        if (n < 64) {
#pragma unroll
          for (int r = 0; r < 4; ++r) fo[(size_t)(mrow + r) * 64 + n] = f2b(a[r] + bv);
        } else {
#pragma unroll
          for (int r = 0; r < 4; ++r) go[(size_t)(mrow + r) * 64 + (n - 64)] = f2b(a[r] + bv);
        }
      }
    }
  }
}

// ---------------- kernel 2: flash attention v12 + setprio (T5) --------------
// attn12 verbatim (128us verified: 128q x 128c block, 8 waves/512thr, grid
// 512 = 2 blocks/CU, Kt=64, 2 barriers/iter) + s_setprio(1) around the S^T
// and PV MFMA clusters. T5 regime check: 2 independent blocks/CU at different
// phases (m191-positive), unlike single-block lockstep (m190-null).
__global__ __launch_bounds__(512, 4) void attn12p(
    const u16* __restrict__ fq, const u16* __restrict__ gk,
    const u16* __restrict__ ht, const float* __restrict__ x,
    const float* __restrict__ gamma_p, float* __restrict__ out) {
  __shared__ u16 lds_g[64 * 64];     // [key][d] swizzled, 8KB
  __shared__ u16 lds_p[128 * 64];    // [q][key] swizzled, 16KB
  __shared__ float lds_red[8 * 64];
  __shared__ float lds_linv[128];

  const int i = blockIdx.x;          // 512 blocks
  const int slice = i & 15;          // XCD x serves slices {x,x+8}: ~3MB in L2
  const int b = slice >> 2, vq = slice & 3;
  const int qb = i >> 4;             // 0..31
  const int q0 = qb * 128, vc0 = vq * 128;

  const int t = threadIdx.x, lane = t & 63, w = t >> 6;   // w: 0..7
  const int l15 = lane & 15, l4 = lane >> 4;
  const int h = w >> 2, kq = w & 3;  // S^T role: q-half, key-quarter
  const float gamma = gamma_p[0];
  const int dmarow = lane >> 3, dmachunk = (lane & 7) ^ (lane >> 3);

  const u16* gkb = gk + (size_t)(b * 4096) * 64;
  const u16* htw = ht + ((size_t)(b * 512 + vc0 + w * 16)) * 4096;

  // preload f frags (B-operand for S^T): this wave's 64-q half
  bf16x8 fB[4][2];
#pragma unroll
  for (int qt = 0; qt < 4; ++qt)
#pragma unroll
    for (int ks = 0; ks < 2; ++ks) {
      const u16* p = fq + (size_t)(b * 4096 + q0 + h * 64 + qt * 16 + l15) * 64 + ks * 32 + l4 * 8;
      fB[qt][ks] = __builtin_bit_cast(bf16x8, *(const u16x8*)p);
    }

  f32x4 oacc[8];                     // 16 c x 128 q (8 q-tiles)
#pragma unroll
  for (int qt = 0; qt < 8; ++qt) oacc[qt] = (f32x4)(0.f);
  float lrun[4] = {0.f, 0.f, 0.f, 0.f};

  auto stage_g = [&](int k0g) {      // stage 64 keys x 64 d; wave stages 8 rows
    const u16* src = gkb + (size_t)(k0g + w * 8 + dmarow) * 64 + dmachunk * 8;
    dma16(src, lds_g + (w * 8) * 64);
  };

  stage_g(0);
  __syncthreads();

  for (int kt = 0; kt < 64; ++kt) {
    const int k0 = kt * 64;
    // ---- S^T: keys kq*16..+16, this wave's 64 q ----
    f32x4 sacc[4];
#pragma unroll
    for (int qt = 0; qt < 4; ++qt) sacc[qt] = (f32x4)(0.f);
    __builtin_amdgcn_s_setprio(1);
#pragma unroll
    for (int ks = 0; ks < 2; ++ks) {
      bf16x8 gA = ldsFrag(lds_g, kq * 16 + l15, ks * 4 + l4);
#pragma unroll
      for (int qt = 0; qt < 4; ++qt) sacc[qt] = MFMA16(gA, fB[qt][ks], sacc[qt]);
    }
    __builtin_amdgcn_s_setprio(0);
    // exp2 (log2e pre-folded), packed b64 P-write, per-lane row-sum partials
#pragma unroll
    for (int qt = 0; qt < 4; ++qt) {
      f32x4 s = sacc[qt];
      f32x4 p;
#pragma unroll
      for (int r = 0; r < 4; ++r) p[r] = __builtin_amdgcn_exp2f(s[r]);
      lrun[qt] += (p[0] + p[1]) + (p[2] + p[3]);
      bf16x4 pb;
#pragma unroll
      for (int r = 0; r < 4; ++r) pb[r] = (__bf16)p[r];
      int row = h * 64 + qt * 16 + l15;        // q within block (0..127)
      int keyb = kq * 16 + (l4 << 2);          // 4 consecutive keys
      u16* dst = lds_p + row * 64 + (((keyb >> 3) ^ (row & 7)) << 3) + (keyb & 7);
      *(u16x4*)dst = __builtin_bit_cast(u16x4, pb);
    }
    __syncthreads();                 // P visible; lds_g reads done
    if (kt < 63) stage_g(k0 + 64);   // overlap g DMA with PV
    // ---- PV: O[q][c] += P . ht, wave owns 16 c x 128 q ----
#pragma unroll
    for (int ks = 0; ks < 2; ++ks) {
      const u16* hp = htw + (size_t)l15 * 4096 + k0 + ks * 32 + l4 * 8;
      bf16x8 hb = __builtin_bit_cast(bf16x8, *(const u16x8*)hp);
      __builtin_amdgcn_s_setprio(1);
#pragma unroll
      for (int qt = 0; qt < 8; ++qt) {
        bf16x8 pf = ldsFrag(lds_p, qt * 16 + l15, ks * 4 + l4);
        oacc[qt] = MFMA16(pf, hb, oacc[qt]);
      }
      __builtin_amdgcn_s_setprio(0);
    }
    __syncthreads();                 // PV lds_p reads done; g(kt+1) drained
  }

  // ---- row-sum reduction: per-wave partials -> cross-wave combine ----
#pragma unroll
  for (int qt = 0; qt < 4; ++qt) {
    lrun[qt] += __shfl_xor(lrun[qt], 16);
    lrun[qt] += __shfl_xor(lrun[qt], 32);
  }
  if (l4 == 0) {
#pragma unroll
    for (int qt = 0; qt < 4; ++qt) lds_red[w * 64 + qt * 16 + l15] = lrun[qt];
  }
  __syncthreads();
  if (t < 128) {                     // q = t; waves h*4..h*4+3 hold its keys
    int hh = t >> 6, ql = t & 63;
    float s = (lds_red[(hh * 4 + 0) * 64 + ql] + lds_red[(hh * 4 + 1) * 64 + ql]) +
              (lds_red[(hh * 4 + 2) * 64 + ql] + lds_red[(hh * 4 + 3) * 64 + ql]);
    lds_linv[t] = 1.0f / s;
  }
  __syncthreads();

  // ---- epilogue: out = x + gamma * O / l ----
#pragma unroll
  for (int qt = 0; qt < 8; ++qt) {
    f32x4 linv = *(const f32x4*)&lds_linv[qt * 16 + (l4 << 2)];
    int c = vc0 + w * 16 + l15;
#pragma unroll
    for (int r = 0; r < 4; ++r) {
      int q = q0 + qt * 16 + (l4 << 2) + r;
      size_t idx = ((size_t)(b * 4096 + q) << 9) + c;
      out[idx] = x[idx] + gamma * oacc[qt][r] * linv[r];
    }
  }
}

extern "C" void kernel_launch(void* const* d_in, const int* in_sizes, int n_in,
                              void* d_out, int out_size, void* d_ws, size_t ws_size,
                              hipStream_t stream) {
  const float* x   = (const float*)d_in[0];
  const float* Wf  = (const float*)d_in[1];
  const float* bfv = (const float*)d_in[2];
  const float* Wg  = (const float*)d_in[3];
  const float* bgv = (const float*)d_in[4];
  const float* Wh  = (const float*)d_in[5];
  const float* bhv = (const float*)d_in[6];
  const float* gam = (const float*)d_in[7];
  float* out = (float*)d_out;

  char* ws = (char*)d_ws;                  // total scratch: ~38.4 MB
  u16*   Wt    = (u16*)(ws);               // 640*512*2    = 655360
  float* biasc = (float*)(ws + 655360);    // 640*4        = 2560
  u16*   fo    = (u16*)(ws + 657920);      // 16384*64*2   = 2097152
  u16*   go    = (u16*)(ws + 2755072);     // 2097152
  u16*   ht    = (u16*)(ws + 4852224);     // 4*512*4096*2 = 16777216
  u16*   xb    = (u16*)(ws + 21629440);    // 16384*512*2  = 16777216

  xpack<<<4176, 256, 0, stream>>>(x, xb, Wf, Wg, Wh, bfv, bgv, bhv, Wt, biasc);
  proj_gemm<<<dim3(128, 5), 256, 0, stream>>>(xb, Wt, biasc, fo, go, ht);
  attn12p<<<512, 512, 0, stream>>>(fo, go, ht, x, gam, out);
}

// Round 13
// 217.969 us; speedup vs baseline: 1.0692x; 1.0252x over previous
//
#include <hip/hip_runtime.h>
#include <stdint.h>

typedef uint16_t u16;
typedef __attribute__((ext_vector_type(8)))  __bf16    bf16x8;
typedef __attribute__((ext_vector_type(4)))  __bf16    bf16x4;
typedef __attribute__((ext_vector_type(8)))  uint16_t  u16x8;
typedef __attribute__((ext_vector_type(4)))  uint16_t  u16x4;
typedef __attribute__((ext_vector_type(4)))  float     f32x4;

#define LOG2E 1.44269504088896340736f
#define MFMA16(a, b, c) __builtin_amdgcn_mfma_f32_16x16x32_bf16((a), (b), (c), 0, 0, 0)

__device__ __forceinline__ u16 f2b(float f) {   // fp32 -> bf16 RNE
  uint32_t u = __builtin_bit_cast(uint32_t, f);
  u += 0x7fffu + ((u >> 16) & 1u);
  return (u16)(u >> 16);
}

// LDS tiles: [rows][64 bf16] = 8 chunks of 16B per row, chunk XOR-swizzled by row&7.
__device__ __forceinline__ bf16x8 ldsFrag(const u16* base, int row, int chunk) {
  const u16* p = base + row * 64 + ((chunk ^ (row & 7)) << 3);
  u16x8 raw = *(const u16x8*)p;
  return __builtin_bit_cast(bf16x8, raw);
}

// async global->LDS DMA, 16B per lane; LDS dest = wave-uniform base + lane*16.
__device__ __forceinline__ void dma16(const u16* g, u16* l) {
  __builtin_amdgcn_global_load_lds(
      (const __attribute__((address_space(1))) uint32_t*)g,
      (__attribute__((address_space(3))) uint32_t*)l, 16, 0, 0);
}

// ---------------- kernel 0: fused xconv + pack_weights ----------------------
// blocks 0..4095: x fp32 -> bf16 (xb). blocks 4096..4175: weight pack
// (Wt[n][k] bf16; n<64: Wf*log2e, n<128: Wg, else Wh; biasc fp32).
__global__ __launch_bounds__(256) void xpack(
    const float* __restrict__ x, u16* __restrict__ xb,
    const float* __restrict__ Wf, const float* __restrict__ Wg,
    const float* __restrict__ Wh, const float* __restrict__ bfv,
    const float* __restrict__ bgv, const float* __restrict__ bhv,
    u16* __restrict__ Wt, float* __restrict__ biasc) {
  __shared__ u16 T[64 * 64];       // [k][n] (pack branch only)
  const int t = threadIdx.x;
  if (blockIdx.x < 4096) {
    // ---- xconv branch ----
    size_t idx = ((size_t)blockIdx.x * 256 + t) * 8;
    f32x4 a0 = *(const f32x4*)(x + idx);
    f32x4 a1 = *(const f32x4*)(x + idx + 4);
    u16x8 v;
#pragma unroll
    for (int i = 0; i < 4; ++i) { v[i] = f2b(a0[i]); v[4 + i] = f2b(a1[i]); }
    *(u16x8*)(xb + idx) = v;
    return;
  }
  // ---- pack branch ----
  const int bid = blockIdx.x - 4096;
  const int nt = bid >> 3;         // 0..9
  const int kt = bid & 7;          // 0..7
  const int n0 = nt * 64, k0 = kt * 64;
  const float* src; int stride, cbase; float scale = 1.0f;
  if (nt == 0)      { src = Wf; stride = 64;  cbase = 0;        scale = LOG2E; }
  else if (nt == 1) { src = Wg; stride = 64;  cbase = 0; }
  else              { src = Wh; stride = 512; cbase = n0 - 128; }
  const int cl = (t & 15) * 4, r0 = t >> 4;
#pragma unroll
  for (int j = 0; j < 4; ++j) {
    int r = r0 + j * 16;
    f32x4 v = *(const f32x4*)(src + (size_t)(k0 + r) * stride + cbase + cl);
    u16x4 o;
#pragma unroll
    for (int i = 0; i < 4; ++i) o[i] = f2b(v[i] * scale);
    *(u16x4*)(T + r * 64 + cl) = o;
  }
  __syncthreads();
  const int n = t >> 2, kq = (t & 3) * 16;
  u16x8 a, b2;
#pragma unroll
  for (int i = 0; i < 8; ++i) { a[i] = T[(kq + i) * 64 + n]; b2[i] = T[(kq + 8 + i) * 64 + n]; }
  *(u16x8*)(Wt + (size_t)(n0 + n) * 512 + k0 + kq) = a;
  *(u16x8*)(Wt + (size_t)(n0 + n) * 512 + k0 + kq + 8) = b2;
  if (kt == 0 && t < 64) {
    float bv = (nt == 0) ? bfv[t] * LOG2E : (nt == 1) ? bgv[t] : bhv[cbase + t];
    biasc[n0 + t] = bv;
  }
}

// ---------------- kernel 1: projection GEMM v2 (BM=128 x BN=64, 4 blk/CU) ---
// [16384 x 512](xb bf16) @ Wt^T. Tile halved vs v1 (128x128 @ 2 blk/CU):
// LDS 24KB, acc 32 VGPR -> __launch_bounds__(256,4) = 16 waves/CU, doubling
// the TLP that hides the stage->barrier->compute stalls (proj ran ~45us at
// 2 blk/CU vs ~22us MFMA floor). Grid 128 x 10; HBM traffic unchanged (L3
// absorbs extra A re-reads). Waves: 2x2 grid, wave tile 64 m x 32 n.
__global__ __launch_bounds__(256, 4) void proj_gemm(
    const u16* __restrict__ xb, const u16* __restrict__ Wt,
    const float* __restrict__ biasc,
    u16* __restrict__ fo, u16* __restrict__ go, u16* __restrict__ ht) {
  __shared__ u16 smem[128 * 64 + 64 * 64];  // lds_a | lds_b; front reused as T
  u16* lds_a = smem;
  u16* lds_b = smem + 128 * 64;
  const int t = threadIdx.x, lane = t & 63, wave = t >> 6;
  const int m0 = blockIdx.x * 128, n0 = blockIdx.y * 64;
  const int wr = wave >> 1, wc = wave & 1;
  const int l15 = lane & 15, l4 = lane >> 4;
  const int dmarow = lane >> 3, dmachunk = (lane & 7) ^ (lane >> 3);

  f32x4 acc[4][2];
#pragma unroll
  for (int i = 0; i < 4; ++i)
#pragma unroll
    for (int j = 0; j < 2; ++j) acc[i][j] = (f32x4)(0.f);

  for (int kb = 0; kb < 8; ++kb) {
    const int k0 = kb * 64;
    if (kb) __syncthreads();               // prior MFMA LDS reads done
#pragma unroll
    for (int ii = 0; ii < 4; ++ii) {       // stage A: 128 xb rows (8/dma)
      int rw = wave * 32 + ii * 8;
      dma16(xb + (size_t)(m0 + rw + dmarow) * 512 + k0 + dmachunk * 8,
            lds_a + rw * 64);
    }
#pragma unroll
    for (int ii = 0; ii < 2; ++ii) {       // stage B: 64 Wt rows
      int rw = wave * 16 + ii * 8;
      dma16(Wt + (size_t)(n0 + rw + dmarow) * 512 + k0 + dmachunk * 8,
            lds_b + rw * 64);
    }
    __syncthreads();                       // drains DMA (vmcnt(0) at barrier)
#pragma unroll
    for (int ks = 0; ks < 2; ++ks) {
      const int chunk = ks * 4 + l4;
      bf16x8 af[4], bq[2];
#pragma unroll
      for (int mt = 0; mt < 4; ++mt) af[mt] = ldsFrag(lds_a, wr * 64 + mt * 16 + l15, chunk);
#pragma unroll
      for (int nt = 0; nt < 2; ++nt) bq[nt] = ldsFrag(lds_b, wc * 32 + nt * 16 + l15, chunk);
#pragma unroll
      for (int mt = 0; mt < 4; ++mt)
#pragma unroll
        for (int nt = 0; nt < 2; ++nt) acc[mt][nt] = MFMA16(af[mt], bq[nt], acc[mt][nt]);
    }
  }

  if (n0 >= 128) {
    // ---- h path: LDS-bounce transpose, coalesced ht stores ----
    __syncthreads();                       // all MFMA LDS reads done
#pragma unroll
    for (int nt = 0; nt < 2; ++nt) {
      int nl = wc * 32 + nt * 16 + l15;    // n within block (0..63)
      float bv = biasc[n0 + nl];
#pragma unroll
      for (int mt = 0; mt < 4; ++mt) {
        int mb = wr * 64 + mt * 16 + (l4 << 2);
        f32x4 a = acc[mt][nt];
        u16x4 v;
#pragma unroll
        for (int r = 0; r < 4; ++r) v[r] = f2b(a[r] + bv);
        // T[nl][m], 16B-chunk swizzled by nl&7
        u16* dst = smem + nl * 128 + (((mb >> 3) ^ (nl & 7)) << 3) + (mb & 7);
        *(u16x4*)dst = v;
      }
    }
    __syncthreads();
    const int bb = m0 >> 12, posb = m0 & 4095;
    const int row0 = t >> 4, c16 = t & 15;
#pragma unroll
    for (int j = 0; j < 4; ++j) {
      int rr = row0 + j * 16;              // 0..63
      u16x8 v = *(const u16x8*)(smem + rr * 128 + ((c16 ^ (rr & 7)) << 3));
      int vcol = n0 - 128 + rr;
      *(u16x8*)(ht + ((size_t)(bb * 512 + vcol) << 12) + posb + c16 * 8) = v;
    }
  } else {
    // ---- f (n0==0) / g (n0==64) path ----
#pragma unroll
    for (int nt = 0; nt < 2; ++nt) {
      int n = wc * 32 + nt * 16 + l15;     // 0..63
      float bv = biasc[n0 + n];
#pragma unroll
      for (int mt = 0; mt < 4; ++mt) {
        int mrow = m0 + wr * 64 + mt * 16 + (l4 << 2);
        f32x4 a = acc[mt][nt];
        if (n0 == 0) {
#pragma unroll
          for (int r = 0; r < 4; ++r) fo[(size_t)(mrow + r) * 64 + n] = f2b(a[r] + bv);
        } else {
#pragma unroll
          for (int r = 0; r < 4; ++r) go[(size_t)(mrow + r) * 64 + n] = f2b(a[r] + bv);
        }
      }
    }
  }
}

// ---------------- kernel 2: flash attention v12 (VERBATIM 128us version) ----
// 128q x 128c block, 8 waves (512 thr), grid 512 = 2 blocks/CU (16 waves/CU).
// S^T: wave (h=w>>2, kq=w&3) does 16 keys x its 64-q half; PV: wave owns
// 16 c x all 128 q. Kt=64, 2 barriers/iter, inline hb L2 loads. No setprio
// (R12 A/B: -2us, m190-negative regime - barrier-locked waves).
__global__ __launch_bounds__(512, 4) void attn12(
    const u16* __restrict__ fq, const u16* __restrict__ gk,
    const u16* __restrict__ ht, const float* __restrict__ x,
    const float* __restrict__ gamma_p, float* __restrict__ out) {
  __shared__ u16 lds_g[64 * 64];     // [key][d] swizzled, 8KB
  __shared__ u16 lds_p[128 * 64];    // [q][key] swizzled, 16KB
  __shared__ float lds_red[8 * 64];
  __shared__ float lds_linv[128];

  const int i = blockIdx.x;          // 512 blocks
  const int slice = i & 15;          // XCD x serves slices {x,x+8}: ~3MB in L2
  const int b = slice >> 2, vq = slice & 3;
  const int qb = i >> 4;             // 0..31
  const int q0 = qb * 128, vc0 = vq * 128;

  const int t = threadIdx.x, lane = t & 63, w = t >> 6;   // w: 0..7
  const int l15 = lane & 15, l4 = lane >> 4;
  const int h = w >> 2, kq = w & 3;  // S^T role: q-half, key-quarter
  const float gamma = gamma_p[0];
  const int dmarow = lane >> 3, dmachunk = (lane & 7) ^ (lane >> 3);

  const u16* gkb = gk + (size_t)(b * 4096) * 64;
  const u16* htw = ht + ((size_t)(b * 512 + vc0 + w * 16)) * 4096;

  // preload f frags (B-operand for S^T): this wave's 64-q half
  bf16x8 fB[4][2];
#pragma unroll
  for (int qt = 0; qt < 4; ++qt)
#pragma unroll
    for (int ks = 0; ks < 2; ++ks) {
      const u16* p = fq + (size_t)(b * 4096 + q0 + h * 64 + qt * 16 + l15) * 64 + ks * 32 + l4 * 8;
      fB[qt][ks] = __builtin_bit_cast(bf16x8, *(const u16x8*)p);
    }

  f32x4 oacc[8];                     // 16 c x 128 q (8 q-tiles)
#pragma unroll
  for (int qt = 0; qt < 8; ++qt) oacc[qt] = (f32x4)(0.f);
  float lrun[4] = {0.f, 0.f, 0.f, 0.f};

  auto stage_g = [&](int k0g) {      // stage 64 keys x 64 d; wave stages 8 rows
    const u16* src = gkb + (size_t)(k0g + w * 8 + dmarow) * 64 + dmachunk * 8;
    dma16(src, lds_g + (w * 8) * 64);
  };

  stage_g(0);
  __syncthreads();

  for (int kt = 0; kt < 64; ++kt) {
    const int k0 = kt * 64;
    // ---- S^T: keys kq*16..+16, this wave's 64 q ----
    f32x4 sacc[4];
#pragma unroll
    for (int qt = 0; qt < 4; ++qt) sacc[qt] = (f32x4)(0.f);
#pragma unroll
    for (int ks = 0; ks < 2; ++ks) {
      bf16x8 gA = ldsFrag(lds_g, kq * 16 + l15, ks * 4 + l4);
#pragma unroll
      for (int qt = 0; qt < 4; ++qt) sacc[qt] = MFMA16(gA, fB[qt][ks], sacc[qt]);
    }
    // exp2 (log2e pre-folded), packed b64 P-write, per-lane row-sum partials
#pragma unroll
    for (int qt = 0; qt < 4; ++qt) {
      f32x4 s = sacc[qt];
      f32x4 p;
#pragma unroll
      for (int r = 0; r < 4; ++r) p[r] = __builtin_amdgcn_exp2f(s[r]);
      lrun[qt] += (p[0] + p[1]) + (p[2] + p[3]);
      bf16x4 pb;
#pragma unroll
      for (int r = 0; r < 4; ++r) pb[r] = (__bf16)p[r];
      int row = h * 64 + qt * 16 + l15;        // q within block (0..127)
      int keyb = kq * 16 + (l4 << 2);          // 4 consecutive keys
      u16* dst = lds_p + row * 64 + (((keyb >> 3) ^ (row & 7)) << 3) + (keyb & 7);
      *(u16x4*)dst = __builtin_bit_cast(u16x4, pb);
    }
    __syncthreads();                 // P visible; lds_g reads done
    if (kt < 63) stage_g(k0 + 64);   // overlap g DMA with PV
    // ---- PV: O[q][c] += P . ht, wave owns 16 c x 128 q ----
#pragma unroll
    for (int ks = 0; ks < 2; ++ks) {
      const u16* hp = htw + (size_t)l15 * 4096 + k0 + ks * 32 + l4 * 8;
      bf16x8 hb = __builtin_bit_cast(bf16x8, *(const u16x8*)hp);
#pragma unroll
      for (int qt = 0; qt < 8; ++qt) {
        bf16x8 pf = ldsFrag(lds_p, qt * 16 + l15, ks * 4 + l4);
        oacc[qt] = MFMA16(pf, hb, oacc[qt]);
      }
    }
    __syncthreads();                 // PV lds_p reads done; g(kt+1) drained
  }

  // ---- row-sum reduction: per-wave partials -> cross-wave combine ----
#pragma unroll
  for (int qt = 0; qt < 4; ++qt) {
    lrun[qt] += __shfl_xor(lrun[qt], 16);
    lrun[qt] += __shfl_xor(lrun[qt], 32);
  }
  if (l4 == 0) {
#pragma unroll
    for (int qt = 0; qt < 4; ++qt) lds_red[w * 64 + qt * 16 + l15] = lrun[qt];
  }
  __syncthreads();
  if (t < 128) {                     // q = t; waves h*4..h*4+3 hold its keys
    int hh = t >> 6, ql = t & 63;
    float s = (lds_red[(hh * 4 + 0) * 64 + ql] + lds_red[(hh * 4 + 1) * 64 + ql]) +
              (lds_red[(hh * 4 + 2) * 64 + ql] + lds_red[(hh * 4 + 3) * 64 + ql]);
    lds_linv[t] = 1.0f / s;
  }
  __syncthreads();

  // ---- epilogue: out = x + gamma * O / l ----
#pragma unroll
  for (int qt = 0; qt < 8; ++qt) {
    f32x4 linv = *(const f32x4*)&lds_linv[qt * 16 + (l4 << 2)];
    int c = vc0 + w * 16 + l15;
#pragma unroll
    for (int r = 0; r < 4; ++r) {
      int q = q0 + qt * 16 + (l4 << 2) + r;
      size_t idx = ((size_t)(b * 4096 + q) << 9) + c;
      out[idx] = x[idx] + gamma * oacc[qt][r] * linv[r];
    }
  }
}

extern "C" void kernel_launch(void* const* d_in, const int* in_sizes, int n_in,
                              void* d_out, int out_size, void* d_ws, size_t ws_size,
                              hipStream_t stream) {
  const float* x   = (const float*)d_in[0];
  const float* Wf  = (const float*)d_in[1];
  const float* bfv = (const float*)d_in[2];
  const float* Wg  = (const float*)d_in[3];
  const float* bgv = (const float*)d_in[4];
  const float* Wh  = (const float*)d_in[5];
  const float* bhv = (const float*)d_in[6];
  const float* gam = (const float*)d_in[7];
  float* out = (float*)d_out;

  char* ws = (char*)d_ws;                  // total scratch: ~38.4 MB
  u16*   Wt    = (u16*)(ws);               // 640*512*2    = 655360
  float* biasc = (float*)(ws + 655360);    // 640*4        = 2560
  u16*   fo    = (u16*)(ws + 657920);      // 16384*64*2   = 2097152
  u16*   go    = (u16*)(ws + 2755072);     // 2097152
  u16*   ht    = (u16*)(ws + 4852224);     // 4*512*4096*2 = 16777216
  u16*   xb    = (u16*)(ws + 21629440);    // 16384*512*2  = 16777216

  xpack<<<4176, 256, 0, stream>>>(x, xb, Wf, Wg, Wh, bfv, bgv, bhv, Wt, biasc);
  proj_gemm<<<dim3(128, 10), 256, 0, stream>>>(xb, Wt, biasc, fo, go, ht);
  attn12<<<512, 512, 0, stream>>>(fo, go, ht, x, gam, out);
}